// Round 4
// baseline (833.135 us; speedup 1.0000x reference)
//
#include <hip/hip_runtime.h>
#include <hip/hip_bf16.h>

// 3-layer GCN, N=100000, E=1000000, dims 64 -> 64 -> 32 -> 16.
// s1 = x@W1 (bf16); a_k = b_k + segment_sum(w_e * s_k[col], row) (bf16);
// s_{k+1} = lrelu(a_k) @ W_{k+1}; final: out = lrelu(a_3) (f32).
// CSR built once per launch; aggregation gather-style, zero float atomics.

__device__ __forceinline__ float lrelu(float v) { return v > 0.0f ? v : 0.25f * v; }
__device__ __forceinline__ float bflo(unsigned u) { return __uint_as_float(u << 16); }
__device__ __forceinline__ float bfhi(unsigned u) { return __uint_as_float(u & 0xffff0000u); }
__device__ __forceinline__ unsigned short f2bf(float f) {          // round-to-nearest-even
    unsigned u = __float_as_uint(f);
    return (unsigned short)((u + 0x7fffu + ((u >> 16) & 1u)) >> 16);
}
__device__ __forceinline__ unsigned packbf(float a, float b) {
    return (unsigned)f2bf(a) | ((unsigned)f2bf(b) << 16);
}

// ---------------- CSR build (unchanged from R3) ----------------

constexpr int SCAN_T = 256;
constexpr int SCAN_PER = 8;
constexpr int SCAN_CHUNK = SCAN_T * SCAN_PER;  // 2048

__global__ void hist_kernel(const int* __restrict__ row, int* __restrict__ cnt, int E) {
    int e = blockIdx.x * blockDim.x + threadIdx.x;
    if (e < E) atomicAdd(&cnt[row[e]], 1);
}

__global__ void scan1_kernel(const int* __restrict__ cnt, int* __restrict__ rs,
                             int* __restrict__ bsum, int N) {
    __shared__ int lds[SCAN_T];
    int t = threadIdx.x;
    int base = blockIdx.x * SCAN_CHUNK + t * SCAN_PER;
    int v[SCAN_PER];
    int run = 0;
#pragma unroll
    for (int j = 0; j < SCAN_PER; ++j) {
        int i = base + j;
        run += (i < N) ? cnt[i] : 0;
        v[j] = run;
    }
    lds[t] = run;
    __syncthreads();
    for (int off = 1; off < SCAN_T; off <<= 1) {
        int add = (t >= off) ? lds[t - off] : 0;
        __syncthreads();
        lds[t] += add;
        __syncthreads();
    }
    int excl = lds[t] - run;
#pragma unroll
    for (int j = 0; j < SCAN_PER; ++j) {
        int i = base + j;
        if (i < N) rs[i] = v[j] + excl;
    }
    if (t == SCAN_T - 1) bsum[blockIdx.x] = lds[t];
}

__global__ void scan2_kernel(const int* __restrict__ bsum, int* __restrict__ bofs, int nb) {
    if (threadIdx.x == 0 && blockIdx.x == 0) {
        int run = 0;
        for (int i = 0; i < nb; ++i) { bofs[i] = run; run += bsum[i]; }
    }
}

__global__ void scan3_kernel(const int* __restrict__ cnt, int* __restrict__ rs,
                             int* __restrict__ cursor, const int* __restrict__ bofs, int N) {
    int i = blockIdx.x * blockDim.x + threadIdx.x;
    if (i >= N) return;
    int e = rs[i] + bofs[i / SCAN_CHUNK];
    rs[i] = e;
    cursor[i] = e - cnt[i];
}

__global__ void scatter_edges_kernel(const int* __restrict__ row, const int* __restrict__ col,
                                     const float* __restrict__ w, int* __restrict__ cursor,
                                     int2* __restrict__ edges, int E) {
    int e = blockIdx.x * blockDim.x + threadIdx.x;
    if (e >= E) return;
    int r = row[e];
    int pos = atomicAdd(&cursor[r], 1);
    edges[pos] = make_int2(col[e], __float_as_int(w[e]));
}

// ---------------- dense transform: out = act(in) @ W, bf16 out ----------------
// Each thread: NPT nodes x 4 output cols -> each W ds_read_b128 feeds NPT*4 FMAs.

template <int K, int M, int NPT, bool ACT, bool INBF16>
__global__ void gemm_kernel(const void* __restrict__ inv, const float* __restrict__ W,
                            __hip_bfloat16* __restrict__ out, int N) {
    constexpr int QM = M / 4;
    __shared__ float Ws[K * M];
    for (int i = threadIdx.x; i < K * M / 4; i += blockDim.x)
        reinterpret_cast<float4*>(Ws)[i] = reinterpret_cast<const float4*>(W)[i];
    __syncthreads();
    int t = blockIdx.x * blockDim.x + threadIdx.x;
    int qc = t & (QM - 1);
    int ngrp = t / QM;
    int nb = ngrp * NPT;
    if (nb >= N) return;

    float acc[NPT][4];
#pragma unroll
    for (int i = 0; i < NPT; ++i) { acc[i][0] = acc[i][1] = acc[i][2] = acc[i][3] = 0.f; }

    const float* inf = (const float*)inv;
    const unsigned short* inb = (const unsigned short*)inv;

#pragma unroll
    for (int k0 = 0; k0 < K; k0 += 4) {
        float4 w0 = *reinterpret_cast<const float4*>(&Ws[(k0 + 0) * M + qc * 4]);
        float4 w1 = *reinterpret_cast<const float4*>(&Ws[(k0 + 1) * M + qc * 4]);
        float4 w2 = *reinterpret_cast<const float4*>(&Ws[(k0 + 2) * M + qc * 4]);
        float4 w3 = *reinterpret_cast<const float4*>(&Ws[(k0 + 3) * M + qc * 4]);
#pragma unroll
        for (int i = 0; i < NPT; ++i) {
            float4 xv;
            if constexpr (INBF16) {
                uint2 u = *reinterpret_cast<const uint2*>(inb + (size_t)(nb + i) * K + k0);
                xv.x = bflo(u.x); xv.y = bfhi(u.x); xv.z = bflo(u.y); xv.w = bfhi(u.y);
            } else {
                xv = *reinterpret_cast<const float4*>(inf + (size_t)(nb + i) * K + k0);
            }
            if (ACT) { xv.x = lrelu(xv.x); xv.y = lrelu(xv.y); xv.z = lrelu(xv.z); xv.w = lrelu(xv.w); }
            acc[i][0] += xv.x * w0.x + xv.y * w1.x + xv.z * w2.x + xv.w * w3.x;
            acc[i][1] += xv.x * w0.y + xv.y * w1.y + xv.z * w2.y + xv.w * w3.y;
            acc[i][2] += xv.x * w0.z + xv.y * w1.z + xv.z * w2.z + xv.w * w3.z;
            acc[i][3] += xv.x * w0.w + xv.y * w1.w + xv.z * w2.w + xv.w * w3.w;
        }
    }
#pragma unroll
    for (int i = 0; i < NPT; ++i) {
        uint2 o;
        o.x = packbf(acc[i][0], acc[i][1]);
        o.y = packbf(acc[i][2], acc[i][3]);
        *reinterpret_cast<uint2*>(out + (size_t)(nb + i) * M + qc * 4) = o;
    }
}

// ---------------- CSR aggregation: wide gathers, G = M/VPT lanes per node ----------------

template <int M, int G, bool ACTOUT, bool OUTBF16>
__global__ void agg_kernel(const int* __restrict__ rs, const int2* __restrict__ edges,
                           const __hip_bfloat16* __restrict__ sup, const float* __restrict__ b,
                           void* __restrict__ outv, int N) {
    constexpr int VPT = M / G;
    static_assert(VPT == 8 || VPT == 4, "VPT must be 8 or 4");
    int tid = blockIdx.x * blockDim.x + threadIdx.x;
    int node = tid / G;
    if (node >= N) return;
    int g = tid - node * G;

    float acc[VPT];
#pragma unroll
    for (int j = 0; j < VPT; ++j) acc[j] = b[g * VPT + j];

    int beg = node ? rs[node - 1] : 0;
    int end = rs[node];
    const unsigned short* su = reinterpret_cast<const unsigned short*>(sup) + g * VPT;

    for (int j0 = beg; j0 < end; j0 += G) {
        int jl = j0 + g;
        int2 ev = edges[jl < end ? jl : end - 1];   // coalesced; clamped lanes never broadcast
        int cnt = min(G, end - j0);
#pragma unroll 4
        for (int jj = 0; jj < cnt; ++jj) {
            int   col = __shfl(ev.x, jj, G);
            float w   = __int_as_float(__shfl(ev.y, jj, G));
            const unsigned short* p = su + (size_t)col * M;
            if constexpr (VPT == 8) {
                uint4 u = *reinterpret_cast<const uint4*>(p);   // 8 bf16 = 16B/lane
                acc[0] += w * bflo(u.x); acc[1] += w * bfhi(u.x);
                acc[2] += w * bflo(u.y); acc[3] += w * bfhi(u.y);
                acc[4] += w * bflo(u.z); acc[5] += w * bfhi(u.z);
                acc[6] += w * bflo(u.w); acc[7] += w * bfhi(u.w);
            } else {
                uint2 u = *reinterpret_cast<const uint2*>(p);   // 4 bf16 = 8B/lane
                acc[0] += w * bflo(u.x); acc[1] += w * bfhi(u.x);
                acc[2] += w * bflo(u.y); acc[3] += w * bfhi(u.y);
            }
        }
    }
    if (ACTOUT) {
#pragma unroll
        for (int j = 0; j < VPT; ++j) acc[j] = lrelu(acc[j]);
    }
    if constexpr (OUTBF16) {
        __hip_bfloat16* out = (__hip_bfloat16*)outv;
        if constexpr (VPT == 8) {
            uint4 o = { packbf(acc[0], acc[1]), packbf(acc[2], acc[3]),
                        packbf(acc[4], acc[5]), packbf(acc[6], acc[7]) };
            *reinterpret_cast<uint4*>(out + (size_t)node * M + g * 8) = o;
        } else {
            uint2 o = { packbf(acc[0], acc[1]), packbf(acc[2], acc[3]) };
            *reinterpret_cast<uint2*>(out + (size_t)node * M + g * 4) = o;
        }
    } else {
        float* out = (float*)outv;
        if constexpr (VPT == 8) {
            float4 o0 = {acc[0], acc[1], acc[2], acc[3]};
            float4 o1 = {acc[4], acc[5], acc[6], acc[7]};
            reinterpret_cast<float4*>(out + (size_t)node * M + g * 8)[0] = o0;
            reinterpret_cast<float4*>(out + (size_t)node * M + g * 8)[1] = o1;
        } else {
            float4 o = {acc[0], acc[1], acc[2], acc[3]};
            *reinterpret_cast<float4*>(out + (size_t)node * M + g * 4) = o;
        }
    }
}

extern "C" void kernel_launch(void* const* d_in, const int* in_sizes, int n_in,
                              void* d_out, int out_size, void* d_ws, size_t ws_size,
                              hipStream_t stream) {
    const float* x    = (const float*)d_in[0];
    const int*   erow = (const int*)  d_in[1];
    const int*   ecol = (const int*)  d_in[2];
    const float* ew   = (const float*)d_in[3];
    const float* W1   = (const float*)d_in[4];
    const float* b1   = (const float*)d_in[5];
    const float* W2   = (const float*)d_in[6];
    const float* b2   = (const float*)d_in[7];
    const float* W3   = (const float*)d_in[8];
    const float* b3   = (const float*)d_in[9];
    float* out = (float*)d_out;

    const int N = in_sizes[0] / 64;   // 100000
    const int E = in_sizes[1];        // 1000000

    // Workspace (bf16 intermediates):
    //   [0,      12.8MB)  s1 (N*64 bf16); later s3 (N*16 bf16)
    //   [12.8,   25.6MB)  a1 (N*64 bf16); later a2 (N*32 bf16)
    //   [25.6,   32.0MB)  s2 (N*32 bf16)
    //   [32.0MB, ...)     CSR: cnt[N], rs[N], cursor[N], bsum[64], bofs[64], edges int2[E]
    char* wsc = (char*)d_ws;
    const size_t SZ64B = (size_t)N * 64 * 2;   // 12.8 MB
    const size_t SZ32B = (size_t)N * 32 * 2;   // 6.4 MB
    __hip_bfloat16* s1 = (__hip_bfloat16*)(wsc);
    __hip_bfloat16* a1 = (__hip_bfloat16*)(wsc + SZ64B);
    __hip_bfloat16* s2 = (__hip_bfloat16*)(wsc + 2 * SZ64B);
    __hip_bfloat16* a2 = (__hip_bfloat16*)(wsc + SZ64B);          // reuse a1 (dead)
    __hip_bfloat16* s3 = (__hip_bfloat16*)(wsc);                  // reuse s1 (dead)

    char* csr = wsc + 2 * SZ64B + SZ32B;
    int*  cnt    = (int*)csr;
    int*  rs     = (int*)(csr + (size_t)N * 4);
    int*  cursor = (int*)(csr + (size_t)N * 8);
    int*  bsum   = (int*)(csr + (size_t)N * 12);
    int*  bofs   = bsum + 64;
    int2* edges  = (int2*)(bofs + 64);

    const int B = 256;
    auto cdiv = [](long a, long b) { return (int)((a + b - 1) / b); };
    const int nb = cdiv(N, SCAN_CHUNK);

    // ---- CSR build ----
    hipMemsetAsync(cnt, 0, (size_t)N * sizeof(int), stream);
    hist_kernel<<<cdiv(E, B), B, 0, stream>>>(erow, cnt, E);
    scan1_kernel<<<nb, SCAN_T, 0, stream>>>(cnt, rs, bsum, N);
    scan2_kernel<<<1, 64, 0, stream>>>(bsum, bofs, nb);
    scan3_kernel<<<cdiv(N, B), B, 0, stream>>>(cnt, rs, cursor, bofs, N);
    scatter_edges_kernel<<<cdiv(E, B), B, 0, stream>>>(erow, ecol, ew, cursor, edges, E);

    // ---- Layer 1: 64 -> 64 ----
    gemm_kernel<64, 64, 8, false, false><<<cdiv((long)(N / 8) * 16, B), B, 0, stream>>>(x, W1, s1, N);
    agg_kernel<64, 8, false, true><<<cdiv((long)N * 8, B), B, 0, stream>>>(rs, edges, s1, b1, a1, N);

    // ---- Layer 2: 64 -> 32 (lrelu on load) ----
    gemm_kernel<64, 32, 8, true, true><<<cdiv((long)(N / 8) * 8, B), B, 0, stream>>>(a1, W2, s2, N);
    agg_kernel<32, 4, false, true><<<cdiv((long)N * 4, B), B, 0, stream>>>(rs, edges, s2, b2, a2, N);

    // ---- Layer 3: 32 -> 16 (lrelu on load; final lrelu fused into agg) ----
    gemm_kernel<32, 16, 8, true, true><<<cdiv((long)(N / 8) * 4, B), B, 0, stream>>>(a2, W3, s3, N);
    agg_kernel<16, 4, true, false><<<cdiv((long)N * 4, B), B, 0, stream>>>(rs, edges, s3, b3, out, N);
}

// Round 5
// 251.385 us; speedup vs baseline: 3.3142x; 3.3142x over previous
//
#include <hip/hip_runtime.h>
#include <hip/hip_bf16.h>

// 3-layer GCN, N=100000, E=1000000, dims 64 -> 64 -> 32 -> 16.
// s1 = x@W1 (bf16); a_k = b_k + segment_sum(w_e * s_k[col], row) (bf16);
// s_{k+1} = lrelu(a_k) @ W_{k+1}; final: out = lrelu(a_3) (f32).
// CSR built once per launch; aggregation gather-style, zero float atomics.
// R5: __launch_bounds__(256) everywhere + NPT=4 — R4's NPT=8 with no bounds
// spilled acc[8][4] to scratch (VGPR capped 64 -> 455MB fetch / 689MB write).

__device__ __forceinline__ float lrelu(float v) { return v > 0.0f ? v : 0.25f * v; }
__device__ __forceinline__ float bflo(unsigned u) { return __uint_as_float(u << 16); }
__device__ __forceinline__ float bfhi(unsigned u) { return __uint_as_float(u & 0xffff0000u); }
__device__ __forceinline__ unsigned short f2bf(float f) {          // round-to-nearest-even
    unsigned u = __float_as_uint(f);
    return (unsigned short)((u + 0x7fffu + ((u >> 16) & 1u)) >> 16);
}
__device__ __forceinline__ unsigned packbf(float a, float b) {
    return (unsigned)f2bf(a) | ((unsigned)f2bf(b) << 16);
}

// ---------------- CSR build ----------------

constexpr int SCAN_T = 256;
constexpr int SCAN_PER = 8;
constexpr int SCAN_CHUNK = SCAN_T * SCAN_PER;  // 2048

__global__ void __launch_bounds__(256)
hist_kernel(const int* __restrict__ row, int* __restrict__ cnt, int E) {
    int e = blockIdx.x * blockDim.x + threadIdx.x;
    if (e < E) atomicAdd(&cnt[row[e]], 1);
}

__global__ void __launch_bounds__(SCAN_T)
scan1_kernel(const int* __restrict__ cnt, int* __restrict__ rs,
             int* __restrict__ bsum, int N) {
    __shared__ int lds[SCAN_T];
    int t = threadIdx.x;
    int base = blockIdx.x * SCAN_CHUNK + t * SCAN_PER;
    int v[SCAN_PER];
    int run = 0;
#pragma unroll
    for (int j = 0; j < SCAN_PER; ++j) {
        int i = base + j;
        run += (i < N) ? cnt[i] : 0;
        v[j] = run;
    }
    lds[t] = run;
    __syncthreads();
    for (int off = 1; off < SCAN_T; off <<= 1) {
        int add = (t >= off) ? lds[t - off] : 0;
        __syncthreads();
        lds[t] += add;
        __syncthreads();
    }
    int excl = lds[t] - run;
#pragma unroll
    for (int j = 0; j < SCAN_PER; ++j) {
        int i = base + j;
        if (i < N) rs[i] = v[j] + excl;
    }
    if (t == SCAN_T - 1) bsum[blockIdx.x] = lds[t];
}

__global__ void __launch_bounds__(64)
scan2_kernel(const int* __restrict__ bsum, int* __restrict__ bofs, int nb) {
    if (threadIdx.x == 0 && blockIdx.x == 0) {
        int run = 0;
        for (int i = 0; i < nb; ++i) { bofs[i] = run; run += bsum[i]; }
    }
}

__global__ void __launch_bounds__(256)
scan3_kernel(const int* __restrict__ cnt, int* __restrict__ rs,
             int* __restrict__ cursor, const int* __restrict__ bofs, int N) {
    int i = blockIdx.x * blockDim.x + threadIdx.x;
    if (i >= N) return;
    int e = rs[i] + bofs[i / SCAN_CHUNK];
    rs[i] = e;
    cursor[i] = e - cnt[i];
}

__global__ void __launch_bounds__(256)
scatter_edges_kernel(const int* __restrict__ row, const int* __restrict__ col,
                     const float* __restrict__ w, int* __restrict__ cursor,
                     int2* __restrict__ edges, int E) {
    int e = blockIdx.x * blockDim.x + threadIdx.x;
    if (e >= E) return;
    int r = row[e];
    int pos = atomicAdd(&cursor[r], 1);
    edges[pos] = make_int2(col[e], __float_as_int(w[e]));
}

// ---------------- dense transform: out = act(in) @ W, bf16 out ----------------
// Each thread: NPT=4 nodes x 4 output cols -> each W ds_read_b128 feeds 16 FMAs.

template <int K, int M, int NPT, bool ACT, bool INBF16>
__global__ void __launch_bounds__(256)
gemm_kernel(const void* __restrict__ inv, const float* __restrict__ W,
            __hip_bfloat16* __restrict__ out, int N) {
    constexpr int QM = M / 4;
    __shared__ float Ws[K * M];
    for (int i = threadIdx.x; i < K * M / 4; i += blockDim.x)
        reinterpret_cast<float4*>(Ws)[i] = reinterpret_cast<const float4*>(W)[i];
    __syncthreads();
    int t = blockIdx.x * blockDim.x + threadIdx.x;
    int qc = t & (QM - 1);
    int ngrp = t / QM;
    int nb = ngrp * NPT;
    if (nb >= N) return;

    float acc[NPT][4];
#pragma unroll
    for (int i = 0; i < NPT; ++i) { acc[i][0] = acc[i][1] = acc[i][2] = acc[i][3] = 0.f; }

    const float* inf = (const float*)inv;
    const unsigned short* inb = (const unsigned short*)inv;

#pragma unroll
    for (int k0 = 0; k0 < K; k0 += 4) {
        float4 w0 = *reinterpret_cast<const float4*>(&Ws[(k0 + 0) * M + qc * 4]);
        float4 w1 = *reinterpret_cast<const float4*>(&Ws[(k0 + 1) * M + qc * 4]);
        float4 w2 = *reinterpret_cast<const float4*>(&Ws[(k0 + 2) * M + qc * 4]);
        float4 w3 = *reinterpret_cast<const float4*>(&Ws[(k0 + 3) * M + qc * 4]);
#pragma unroll
        for (int i = 0; i < NPT; ++i) {
            float4 xv;
            if constexpr (INBF16) {
                uint2 u = *reinterpret_cast<const uint2*>(inb + (size_t)(nb + i) * K + k0);
                xv.x = bflo(u.x); xv.y = bfhi(u.x); xv.z = bflo(u.y); xv.w = bfhi(u.y);
            } else {
                xv = *reinterpret_cast<const float4*>(inf + (size_t)(nb + i) * K + k0);
            }
            if (ACT) { xv.x = lrelu(xv.x); xv.y = lrelu(xv.y); xv.z = lrelu(xv.z); xv.w = lrelu(xv.w); }
            acc[i][0] += xv.x * w0.x + xv.y * w1.x + xv.z * w2.x + xv.w * w3.x;
            acc[i][1] += xv.x * w0.y + xv.y * w1.y + xv.z * w2.y + xv.w * w3.y;
            acc[i][2] += xv.x * w0.z + xv.y * w1.z + xv.z * w2.z + xv.w * w3.z;
            acc[i][3] += xv.x * w0.w + xv.y * w1.w + xv.z * w2.w + xv.w * w3.w;
        }
    }
#pragma unroll
    for (int i = 0; i < NPT; ++i) {
        uint2 o;
        o.x = packbf(acc[i][0], acc[i][1]);
        o.y = packbf(acc[i][2], acc[i][3]);
        *reinterpret_cast<uint2*>(out + (size_t)(nb + i) * M + qc * 4) = o;
    }
}

// ---------------- CSR aggregation: wide gathers, G = M/VPT lanes per node ----------------

template <int M, int G, bool ACTOUT, bool OUTBF16>
__global__ void __launch_bounds__(256)
agg_kernel(const int* __restrict__ rs, const int2* __restrict__ edges,
           const __hip_bfloat16* __restrict__ sup, const float* __restrict__ b,
           void* __restrict__ outv, int N) {
    constexpr int VPT = M / G;
    static_assert(VPT == 8 || VPT == 4, "VPT must be 8 or 4");
    int tid = blockIdx.x * blockDim.x + threadIdx.x;
    int node = tid / G;
    if (node >= N) return;
    int g = tid - node * G;

    float acc[VPT];
#pragma unroll
    for (int j = 0; j < VPT; ++j) acc[j] = b[g * VPT + j];

    int beg = node ? rs[node - 1] : 0;
    int end = rs[node];
    const unsigned short* su = reinterpret_cast<const unsigned short*>(sup) + g * VPT;

    for (int j0 = beg; j0 < end; j0 += G) {
        int jl = j0 + g;
        int2 ev = edges[jl < end ? jl : end - 1];   // coalesced; clamped lanes never broadcast
        int cnt = min(G, end - j0);
#pragma unroll 4
        for (int jj = 0; jj < cnt; ++jj) {
            int   col = __shfl(ev.x, jj, G);
            float w   = __int_as_float(__shfl(ev.y, jj, G));
            const unsigned short* p = su + (size_t)col * M;
            if constexpr (VPT == 8) {
                uint4 u = *reinterpret_cast<const uint4*>(p);   // 8 bf16 = 16B/lane
                acc[0] += w * bflo(u.x); acc[1] += w * bfhi(u.x);
                acc[2] += w * bflo(u.y); acc[3] += w * bfhi(u.y);
                acc[4] += w * bflo(u.z); acc[5] += w * bfhi(u.z);
                acc[6] += w * bflo(u.w); acc[7] += w * bfhi(u.w);
            } else {
                uint2 u = *reinterpret_cast<const uint2*>(p);   // 4 bf16 = 8B/lane
                acc[0] += w * bflo(u.x); acc[1] += w * bfhi(u.x);
                acc[2] += w * bflo(u.y); acc[3] += w * bfhi(u.y);
            }
        }
    }
    if (ACTOUT) {
#pragma unroll
        for (int j = 0; j < VPT; ++j) acc[j] = lrelu(acc[j]);
    }
    if constexpr (OUTBF16) {
        __hip_bfloat16* out = (__hip_bfloat16*)outv;
        if constexpr (VPT == 8) {
            uint4 o = { packbf(acc[0], acc[1]), packbf(acc[2], acc[3]),
                        packbf(acc[4], acc[5]), packbf(acc[6], acc[7]) };
            *reinterpret_cast<uint4*>(out + (size_t)node * M + g * 8) = o;
        } else {
            uint2 o = { packbf(acc[0], acc[1]), packbf(acc[2], acc[3]) };
            *reinterpret_cast<uint2*>(out + (size_t)node * M + g * 4) = o;
        }
    } else {
        float* out = (float*)outv;
        if constexpr (VPT == 8) {
            float4 o0 = {acc[0], acc[1], acc[2], acc[3]};
            float4 o1 = {acc[4], acc[5], acc[6], acc[7]};
            reinterpret_cast<float4*>(out + (size_t)node * M + g * 8)[0] = o0;
            reinterpret_cast<float4*>(out + (size_t)node * M + g * 8)[1] = o1;
        } else {
            float4 o = {acc[0], acc[1], acc[2], acc[3]};
            *reinterpret_cast<float4*>(out + (size_t)node * M + g * 4) = o;
        }
    }
}

extern "C" void kernel_launch(void* const* d_in, const int* in_sizes, int n_in,
                              void* d_out, int out_size, void* d_ws, size_t ws_size,
                              hipStream_t stream) {
    const float* x    = (const float*)d_in[0];
    const int*   erow = (const int*)  d_in[1];
    const int*   ecol = (const int*)  d_in[2];
    const float* ew   = (const float*)d_in[3];
    const float* W1   = (const float*)d_in[4];
    const float* b1   = (const float*)d_in[5];
    const float* W2   = (const float*)d_in[6];
    const float* b2   = (const float*)d_in[7];
    const float* W3   = (const float*)d_in[8];
    const float* b3   = (const float*)d_in[9];
    float* out = (float*)d_out;

    const int N = in_sizes[0] / 64;   // 100000
    const int E = in_sizes[1];        // 1000000

    // Workspace (bf16 intermediates):
    //   [0,      12.8MB)  s1 (N*64 bf16); later s3 (N*16 bf16)
    //   [12.8,   25.6MB)  a1 (N*64 bf16); later a2 (N*32 bf16)
    //   [25.6,   32.0MB)  s2 (N*32 bf16)
    //   [32.0MB, ...)     CSR: cnt[N], rs[N], cursor[N], bsum[64], bofs[64], edges int2[E]
    char* wsc = (char*)d_ws;
    const size_t SZ64B = (size_t)N * 64 * 2;   // 12.8 MB
    const size_t SZ32B = (size_t)N * 32 * 2;   // 6.4 MB
    __hip_bfloat16* s1 = (__hip_bfloat16*)(wsc);
    __hip_bfloat16* a1 = (__hip_bfloat16*)(wsc + SZ64B);
    __hip_bfloat16* s2 = (__hip_bfloat16*)(wsc + 2 * SZ64B);
    __hip_bfloat16* a2 = (__hip_bfloat16*)(wsc + SZ64B);          // reuse a1 (dead)
    __hip_bfloat16* s3 = (__hip_bfloat16*)(wsc);                  // reuse s1 (dead)

    char* csr = wsc + 2 * SZ64B + SZ32B;
    int*  cnt    = (int*)csr;
    int*  rs     = (int*)(csr + (size_t)N * 4);
    int*  cursor = (int*)(csr + (size_t)N * 8);
    int*  bsum   = (int*)(csr + (size_t)N * 12);
    int*  bofs   = bsum + 64;
    int2* edges  = (int2*)(bofs + 64);

    const int B = 256;
    auto cdiv = [](long a, long b) { return (int)((a + b - 1) / b); };
    const int nb = cdiv(N, SCAN_CHUNK);

    // ---- CSR build ----
    hipMemsetAsync(cnt, 0, (size_t)N * sizeof(int), stream);
    hist_kernel<<<cdiv(E, B), B, 0, stream>>>(erow, cnt, E);
    scan1_kernel<<<nb, SCAN_T, 0, stream>>>(cnt, rs, bsum, N);
    scan2_kernel<<<1, 64, 0, stream>>>(bsum, bofs, nb);
    scan3_kernel<<<cdiv(N, B), B, 0, stream>>>(cnt, rs, cursor, bofs, N);
    scatter_edges_kernel<<<cdiv(E, B), B, 0, stream>>>(erow, ecol, ew, cursor, edges, E);

    // ---- Layer 1: 64 -> 64 ----
    gemm_kernel<64, 64, 4, false, false><<<cdiv((long)(N / 4) * 16, B), B, 0, stream>>>(x, W1, s1, N);
    agg_kernel<64, 8, false, true><<<cdiv((long)N * 8, B), B, 0, stream>>>(rs, edges, s1, b1, a1, N);

    // ---- Layer 2: 64 -> 32 (lrelu on load) ----
    gemm_kernel<64, 32, 4, true, true><<<cdiv((long)(N / 4) * 8, B), B, 0, stream>>>(a1, W2, s2, N);
    agg_kernel<32, 4, false, true><<<cdiv((long)N * 4, B), B, 0, stream>>>(rs, edges, s2, b2, a2, N);

    // ---- Layer 3: 32 -> 16 (lrelu on load; final lrelu fused into agg) ----
    gemm_kernel<32, 16, 4, true, true><<<cdiv((long)(N / 4) * 4, B), B, 0, stream>>>(a2, W3, s3, N);
    agg_kernel<16, 4, true, false><<<cdiv((long)N * 4, B), B, 0, stream>>>(rs, edges, s3, b3, out, N);
}

// Round 6
// 199.165 us; speedup vs baseline: 4.1831x; 1.2622x over previous
//
#include <hip/hip_runtime.h>
#include <hip/hip_bf16.h>

// 3-layer GCN, N=100000, E=1000000, dims 64 -> 64 -> 32 -> 16.
// s1 = x@W1 (bf16); a_k = b_k + segment_sum(w_e * s_k[col], row) (bf16);
// s_{k+1} = lrelu(a_k) @ W_{k+1}; final: out = lrelu(a_3) (f32).
// CSR built once per launch, gather-style aggregation, zero float atomics.
// R6: CSR build = ONE atomic pass (rank = atomicAdd(cnt[row],1), which is also
// the histogram) + atomic-free positioned store; EPT=4 independent chains/thread
// for MLP against ~900cy device-atomic latency. R5 had 2M atomics (hist+scatter)
// with 1 dependent chain/thread -> 68us scatter + ~40us hist.

__device__ __forceinline__ float lrelu(float v) { return v > 0.0f ? v : 0.25f * v; }
__device__ __forceinline__ float bflo(unsigned u) { return __uint_as_float(u << 16); }
__device__ __forceinline__ float bfhi(unsigned u) { return __uint_as_float(u & 0xffff0000u); }
__device__ __forceinline__ unsigned short f2bf(float f) {          // round-to-nearest-even
    unsigned u = __float_as_uint(f);
    return (unsigned short)((u + 0x7fffu + ((u >> 16) & 1u)) >> 16);
}
__device__ __forceinline__ unsigned packbf(float a, float b) {
    return (unsigned)f2bf(a) | ((unsigned)f2bf(b) << 16);
}

// ---------------- CSR build ----------------

constexpr int SCAN_T = 256;
constexpr int SCAN_PER = 8;
constexpr int SCAN_CHUNK = SCAN_T * SCAN_PER;  // 2048

// rank[e] = atomicAdd(cnt[row[e]], 1). EPT independent atomic chains per thread.
template <int EPT>
__global__ void __launch_bounds__(256)
rank_kernel(const int* __restrict__ row, int* __restrict__ cnt,
            int* __restrict__ rank, int E) {
    int base = blockIdx.x * (blockDim.x * EPT) + threadIdx.x;
    int r[EPT];
    int rk[EPT];
#pragma unroll
    for (int k = 0; k < EPT; ++k) {
        int e = base + k * 256;
        r[k] = (e < E) ? row[e] : -1;              // coalesced
    }
#pragma unroll
    for (int k = 0; k < EPT; ++k) {
        if (r[k] >= 0) rk[k] = atomicAdd(&cnt[r[k]], 1);   // EPT independent atomics in flight
    }
#pragma unroll
    for (int k = 0; k < EPT; ++k) {
        int e = base + k * 256;
        if (e < E) rank[e] = rk[k];                // coalesced
    }
}

__global__ void __launch_bounds__(SCAN_T)
scan1_kernel(const int* __restrict__ cnt, int* __restrict__ rs,
             int* __restrict__ bsum, int N) {
    __shared__ int lds[SCAN_T];
    int t = threadIdx.x;
    int base = blockIdx.x * SCAN_CHUNK + t * SCAN_PER;
    int v[SCAN_PER];
    int run = 0;
#pragma unroll
    for (int j = 0; j < SCAN_PER; ++j) {
        int i = base + j;
        run += (i < N) ? cnt[i] : 0;
        v[j] = run;
    }
    lds[t] = run;
    __syncthreads();
    for (int off = 1; off < SCAN_T; off <<= 1) {
        int add = (t >= off) ? lds[t - off] : 0;
        __syncthreads();
        lds[t] += add;
        __syncthreads();
    }
    int excl = lds[t] - run;
#pragma unroll
    for (int j = 0; j < SCAN_PER; ++j) {
        int i = base + j;
        if (i < N) rs[i] = v[j] + excl;
    }
    if (t == SCAN_T - 1) bsum[blockIdx.x] = lds[t];
}

__global__ void __launch_bounds__(64)
scan2_kernel(const int* __restrict__ bsum, int* __restrict__ bofs, int nb) {
    if (threadIdx.x == 0 && blockIdx.x == 0) {
        int run = 0;
        for (int i = 0; i < nb; ++i) { bofs[i] = run; run += bsum[i]; }
    }
}

__global__ void __launch_bounds__(256)
scan3_kernel(const int* __restrict__ cnt, int* __restrict__ rs,
             int* __restrict__ start, const int* __restrict__ bofs, int N) {
    int i = blockIdx.x * blockDim.x + threadIdx.x;
    if (i >= N) return;
    int e = rs[i] + bofs[i / SCAN_CHUNK];
    rs[i] = e;                 // inclusive ends (agg reads these)
    start[i] = e - cnt[i];     // exclusive starts (place reads these)
}

// edges[start[row[e]] + rank[e]] = {col, w}. No atomics.
template <int EPT>
__global__ void __launch_bounds__(256)
place_kernel(const int* __restrict__ row, const int* __restrict__ col,
             const float* __restrict__ w, const int* __restrict__ start,
             const int* __restrict__ rank, int2* __restrict__ edges, int E) {
    int base = blockIdx.x * (blockDim.x * EPT) + threadIdx.x;
    int r[EPT], c[EPT], rk[EPT];
    float wv[EPT];
#pragma unroll
    for (int k = 0; k < EPT; ++k) {
        int e = base + k * 256;
        if (e < E) { r[k] = row[e]; c[k] = col[e]; wv[k] = w[e]; rk[k] = rank[e]; }
        else r[k] = -1;
    }
    int st[EPT];
#pragma unroll
    for (int k = 0; k < EPT; ++k) if (r[k] >= 0) st[k] = start[r[k]];   // EPT independent gathers
#pragma unroll
    for (int k = 0; k < EPT; ++k)
        if (r[k] >= 0) edges[st[k] + rk[k]] = make_int2(c[k], __float_as_int(wv[k]));
}

// ---------------- dense transform: out = act(in) @ W, bf16 out ----------------
// NPT=4 nodes x 4 cols per thread -> each W ds_read_b128 feeds 16 FMAs.

template <int K, int M, int NPT, bool ACT, bool INBF16>
__global__ void __launch_bounds__(256)
gemm_kernel(const void* __restrict__ inv, const float* __restrict__ W,
            __hip_bfloat16* __restrict__ out, int N) {
    constexpr int QM = M / 4;
    __shared__ float Ws[K * M];
    for (int i = threadIdx.x; i < K * M / 4; i += blockDim.x)
        reinterpret_cast<float4*>(Ws)[i] = reinterpret_cast<const float4*>(W)[i];
    __syncthreads();
    int t = blockIdx.x * blockDim.x + threadIdx.x;
    int qc = t & (QM - 1);
    int ngrp = t / QM;
    int nb = ngrp * NPT;
    if (nb >= N) return;

    float acc[NPT][4];
#pragma unroll
    for (int i = 0; i < NPT; ++i) { acc[i][0] = acc[i][1] = acc[i][2] = acc[i][3] = 0.f; }

    const float* inf = (const float*)inv;
    const unsigned short* inb = (const unsigned short*)inv;

#pragma unroll
    for (int k0 = 0; k0 < K; k0 += 4) {
        float4 w0 = *reinterpret_cast<const float4*>(&Ws[(k0 + 0) * M + qc * 4]);
        float4 w1 = *reinterpret_cast<const float4*>(&Ws[(k0 + 1) * M + qc * 4]);
        float4 w2 = *reinterpret_cast<const float4*>(&Ws[(k0 + 2) * M + qc * 4]);
        float4 w3 = *reinterpret_cast<const float4*>(&Ws[(k0 + 3) * M + qc * 4]);
#pragma unroll
        for (int i = 0; i < NPT; ++i) {
            float4 xv;
            if constexpr (INBF16) {
                uint2 u = *reinterpret_cast<const uint2*>(inb + (size_t)(nb + i) * K + k0);
                xv.x = bflo(u.x); xv.y = bfhi(u.x); xv.z = bflo(u.y); xv.w = bfhi(u.y);
            } else {
                xv = *reinterpret_cast<const float4*>(inf + (size_t)(nb + i) * K + k0);
            }
            if (ACT) { xv.x = lrelu(xv.x); xv.y = lrelu(xv.y); xv.z = lrelu(xv.z); xv.w = lrelu(xv.w); }
            acc[i][0] += xv.x * w0.x + xv.y * w1.x + xv.z * w2.x + xv.w * w3.x;
            acc[i][1] += xv.x * w0.y + xv.y * w1.y + xv.z * w2.y + xv.w * w3.y;
            acc[i][2] += xv.x * w0.z + xv.y * w1.z + xv.z * w2.z + xv.w * w3.z;
            acc[i][3] += xv.x * w0.w + xv.y * w1.w + xv.z * w2.w + xv.w * w3.w;
        }
    }
#pragma unroll
    for (int i = 0; i < NPT; ++i) {
        uint2 o;
        o.x = packbf(acc[i][0], acc[i][1]);
        o.y = packbf(acc[i][2], acc[i][3]);
        *reinterpret_cast<uint2*>(out + (size_t)(nb + i) * M + qc * 4) = o;
    }
}

// ---------------- CSR aggregation: wide gathers, G = M/VPT lanes per node ----------------

template <int M, int G, bool ACTOUT, bool OUTBF16>
__global__ void __launch_bounds__(256)
agg_kernel(const int* __restrict__ rs, const int2* __restrict__ edges,
           const __hip_bfloat16* __restrict__ sup, const float* __restrict__ b,
           void* __restrict__ outv, int N) {
    constexpr int VPT = M / G;
    static_assert(VPT == 8 || VPT == 4, "VPT must be 8 or 4");
    int tid = blockIdx.x * blockDim.x + threadIdx.x;
    int node = tid / G;
    if (node >= N) return;
    int g = tid - node * G;

    float acc[VPT];
#pragma unroll
    for (int j = 0; j < VPT; ++j) acc[j] = b[g * VPT + j];

    int beg = node ? rs[node - 1] : 0;
    int end = rs[node];
    const unsigned short* su = reinterpret_cast<const unsigned short*>(sup) + g * VPT;

    for (int j0 = beg; j0 < end; j0 += G) {
        int jl = j0 + g;
        int2 ev = edges[jl < end ? jl : end - 1];   // coalesced; clamped lanes never broadcast
        int cnt = min(G, end - j0);
#pragma unroll 4
        for (int jj = 0; jj < cnt; ++jj) {
            int   col = __shfl(ev.x, jj, G);
            float w   = __int_as_float(__shfl(ev.y, jj, G));
            const unsigned short* p = su + (size_t)col * M;
            if constexpr (VPT == 8) {
                uint4 u = *reinterpret_cast<const uint4*>(p);   // 8 bf16 = 16B/lane
                acc[0] += w * bflo(u.x); acc[1] += w * bfhi(u.x);
                acc[2] += w * bflo(u.y); acc[3] += w * bfhi(u.y);
                acc[4] += w * bflo(u.z); acc[5] += w * bfhi(u.z);
                acc[6] += w * bflo(u.w); acc[7] += w * bfhi(u.w);
            } else {
                uint2 u = *reinterpret_cast<const uint2*>(p);   // 4 bf16 = 8B/lane
                acc[0] += w * bflo(u.x); acc[1] += w * bfhi(u.x);
                acc[2] += w * bflo(u.y); acc[3] += w * bfhi(u.y);
            }
        }
    }
    if (ACTOUT) {
#pragma unroll
        for (int j = 0; j < VPT; ++j) acc[j] = lrelu(acc[j]);
    }
    if constexpr (OUTBF16) {
        __hip_bfloat16* out = (__hip_bfloat16*)outv;
        if constexpr (VPT == 8) {
            uint4 o = { packbf(acc[0], acc[1]), packbf(acc[2], acc[3]),
                        packbf(acc[4], acc[5]), packbf(acc[6], acc[7]) };
            *reinterpret_cast<uint4*>(out + (size_t)node * M + g * 8) = o;
        } else {
            uint2 o = { packbf(acc[0], acc[1]), packbf(acc[2], acc[3]) };
            *reinterpret_cast<uint2*>(out + (size_t)node * M + g * 4) = o;
        }
    } else {
        float* out = (float*)outv;
        if constexpr (VPT == 8) {
            float4 o0 = {acc[0], acc[1], acc[2], acc[3]};
            float4 o1 = {acc[4], acc[5], acc[6], acc[7]};
            reinterpret_cast<float4*>(out + (size_t)node * M + g * 8)[0] = o0;
            reinterpret_cast<float4*>(out + (size_t)node * M + g * 8)[1] = o1;
        } else {
            float4 o = {acc[0], acc[1], acc[2], acc[3]};
            *reinterpret_cast<float4*>(out + (size_t)node * M + g * 4) = o;
        }
    }
}

extern "C" void kernel_launch(void* const* d_in, const int* in_sizes, int n_in,
                              void* d_out, int out_size, void* d_ws, size_t ws_size,
                              hipStream_t stream) {
    const float* x    = (const float*)d_in[0];
    const int*   erow = (const int*)  d_in[1];
    const int*   ecol = (const int*)  d_in[2];
    const float* ew   = (const float*)d_in[3];
    const float* W1   = (const float*)d_in[4];
    const float* b1   = (const float*)d_in[5];
    const float* W2   = (const float*)d_in[6];
    const float* b2   = (const float*)d_in[7];
    const float* W3   = (const float*)d_in[8];
    const float* b3   = (const float*)d_in[9];
    float* out = (float*)d_out;

    const int N = in_sizes[0] / 64;   // 100000
    const int E = in_sizes[1];        // 1000000

    // Workspace:
    //   [0,      12.8MB)  s1 (N*64 bf16); later s3 (N*16 bf16)
    //   [12.8,   25.6MB)  a1 (N*64 bf16); later a2 (N*32 bf16)
    //   [25.6,   32.0MB)  s2 (N*32 bf16)
    //   [32.0MB, ...)     CSR: cnt[N], rs[N], start[N], bsum[64], bofs[64],
    //                          rank[E] (4MB), edges int2[E] (8MB)
    char* wsc = (char*)d_ws;
    const size_t SZ64B = (size_t)N * 64 * 2;   // 12.8 MB
    const size_t SZ32B = (size_t)N * 32 * 2;   // 6.4 MB
    __hip_bfloat16* s1 = (__hip_bfloat16*)(wsc);
    __hip_bfloat16* a1 = (__hip_bfloat16*)(wsc + SZ64B);
    __hip_bfloat16* s2 = (__hip_bfloat16*)(wsc + 2 * SZ64B);
    __hip_bfloat16* a2 = (__hip_bfloat16*)(wsc + SZ64B);          // reuse a1 (dead)
    __hip_bfloat16* s3 = (__hip_bfloat16*)(wsc);                  // reuse s1 (dead)

    char* csr = wsc + 2 * SZ64B + SZ32B;
    int*  cnt   = (int*)csr;
    int*  rs    = (int*)(csr + (size_t)N * 4);
    int*  start = (int*)(csr + (size_t)N * 8);
    int*  bsum  = (int*)(csr + (size_t)N * 12);
    int*  bofs  = bsum + 64;
    int*  rank  = bofs + 64;
    int2* edges = (int2*)(rank + E);

    const int B = 256;
    constexpr int EPT = 4;
    auto cdiv = [](long a, long b) { return (int)((a + b - 1) / b); };
    const int nb = cdiv(N, SCAN_CHUNK);

    // ---- CSR build ----
    hipMemsetAsync(cnt, 0, (size_t)N * sizeof(int), stream);
    rank_kernel<EPT><<<cdiv(E, B * EPT), B, 0, stream>>>(erow, cnt, rank, E);
    scan1_kernel<<<nb, SCAN_T, 0, stream>>>(cnt, rs, bsum, N);
    scan2_kernel<<<1, 64, 0, stream>>>(bsum, bofs, nb);
    scan3_kernel<<<cdiv(N, B), B, 0, stream>>>(cnt, rs, start, bofs, N);
    place_kernel<EPT><<<cdiv(E, B * EPT), B, 0, stream>>>(erow, ecol, ew, start, rank, edges, E);

    // ---- Layer 1: 64 -> 64 ----
    gemm_kernel<64, 64, 4, false, false><<<cdiv((long)(N / 4) * 16, B), B, 0, stream>>>(x, W1, s1, N);
    agg_kernel<64, 8, false, true><<<cdiv((long)N * 8, B), B, 0, stream>>>(rs, edges, s1, b1, a1, N);

    // ---- Layer 2: 64 -> 32 (lrelu on load) ----
    gemm_kernel<64, 32, 4, true, true><<<cdiv((long)(N / 4) * 8, B), B, 0, stream>>>(a1, W2, s2, N);
    agg_kernel<32, 4, false, true><<<cdiv((long)N * 4, B), B, 0, stream>>>(rs, edges, s2, b2, a2, N);

    // ---- Layer 3: 32 -> 16 (lrelu on load; final lrelu fused into agg) ----
    gemm_kernel<32, 16, 4, true, true><<<cdiv((long)(N / 4) * 4, B), B, 0, stream>>>(a2, W3, s3, N);
    agg_kernel<16, 4, true, false><<<cdiv((long)N * 4, B), B, 0, stream>>>(rs, edges, s3, b3, out, N);
}